// Round 2
// baseline (366.688 us; speedup 1.0000x reference)
//
#include <hip/hip_runtime.h>
#include <hip/hip_bf16.h>

#define DM 2048
#define DS 128
#define NB 8
#define TT 2048
#define MM (NB*TT)   // 16384 tokens

using f32x4 = __attribute__((ext_vector_type(4))) float;
using s16x8 = __attribute__((ext_vector_type(8))) short;

__device__ __forceinline__ short f2bf(float f) {
    __hip_bfloat16 h = __float2bfloat16(f);
    return *reinterpret_cast<short*>(&h);
}

// ---------------------------------------------------------------- k0: cast B,C -> bf16
__global__ void k_cast(const float* __restrict__ Bm, const float* __restrict__ Cm,
                       short* __restrict__ Bb, short* __restrict__ Cb) {
    int t = blockIdx.x * blockDim.x + threadIdx.x;   // 0..131071
    const int nB = (DS * DM) / 4;                    // 65536 float4 groups per matrix
    const float4* src;
    short* dst;
    int i;
    if (t < nB) { src = (const float4*)Bm; dst = Bb; i = t; }
    else        { src = (const float4*)Cm; dst = Cb; i = t - nB; }
    float4 v = src[i];
    short4 o;
    o.x = f2bf(v.x); o.y = f2bf(v.y); o.z = f2bf(v.z); o.w = f2bf(v.w);
    *reinterpret_cast<short4*>(&dst[i * 4]) = o;
}

// ---------------------------------------------------------------- k1: u = x @ B^T (split-K=2)
// grid (256 m-tiles, 2 k-halves), 256 threads (4 waves), BM=64, BN=128, KB=64
__global__ __launch_bounds__(256, 2) void k1_proj(
        const float* __restrict__ x, const short* __restrict__ Bb,
        float* __restrict__ u_parts) {
    __shared__ short xs[64][72];    // pad 64->72: 144B row stride, 16B aligned, 2-way bank alias only
    __shared__ short bs[128][72];
    const int tok0 = blockIdx.x * 64;
    const int p    = blockIdx.y;
    const int kbase = p * 1024;
    const int tid = threadIdx.x;
    const int wv = tid >> 6, l = tid & 63;
    const int r = l & 15, g = l >> 4;
    const int c4 = tid & 15, r0 = tid >> 4;

    f32x4 acc[8] = {};   // 8 n-tiles of 16x16 per wave (wave tile 16 tok x 128 n)

    for (int kt = 0; kt < 1024; kt += 64) {
        const int k0 = kbase + kt;
        // stage x tile [64 rows][64 k] fp32 -> bf16
        #pragma unroll
        for (int ps = 0; ps < 4; ++ps) {
            int row = ps * 16 + r0;
            float4 v = *reinterpret_cast<const float4*>(
                &x[(size_t)(tok0 + row) * DM + k0 + c4 * 4]);
            short4 o;
            o.x = f2bf(v.x); o.y = f2bf(v.y); o.z = f2bf(v.z); o.w = f2bf(v.w);
            *reinterpret_cast<short4*>(&xs[row][c4 * 4]) = o;
        }
        // stage B tile [128 n][64 k] bf16 (16B chunks)
        #pragma unroll
        for (int ps = 0; ps < 4; ++ps) {
            int chunk = ps * 256 + tid;
            int n = chunk >> 3, cc = chunk & 7;
            int4 v = *reinterpret_cast<const int4*>(&Bb[(size_t)n * DM + k0 + cc * 8]);
            *reinterpret_cast<int4*>(&bs[n][cc * 8]) = v;
        }
        __syncthreads();
        #pragma unroll
        for (int ks = 0; ks < 2; ++ks) {
            s16x8 a = *reinterpret_cast<const s16x8*>(&xs[wv * 16 + r][ks * 32 + g * 8]);
            #pragma unroll
            for (int nt = 0; nt < 8; ++nt) {
                s16x8 b = *reinterpret_cast<const s16x8*>(&bs[nt * 16 + r][ks * 32 + g * 8]);
                acc[nt] = __builtin_amdgcn_mfma_f32_16x16x32_bf16(a, b, acc[nt], 0, 0, 0);
            }
        }
        __syncthreads();
    }
    // store: D layout col = lane&15, row = (lane>>4)*4 + reg
    float* up = u_parts + (size_t)p * MM * DS;
    #pragma unroll
    for (int nt = 0; nt < 8; ++nt) {
        #pragma unroll
        for (int j = 0; j < 4; ++j) {
            int row = tok0 + wv * 16 + g * 4 + j;
            int col = nt * 16 + r;
            up[(size_t)row * DS + col] = acc[nt][j];
        }
    }
}

// ---------------------------------------------------------------- k2: chunked scan (64 chunks of L=32)
__global__ void k2_partial(const float* __restrict__ u, const float* __restrict__ logA,
                           float* __restrict__ spart) {
    int bc = blockIdx.x;             // b*64 + c
    int n = threadIdx.x;
    float A = expf(-expf(logA[n]));
    int tok0 = (bc >> 6) * TT + (bc & 63) * 32;
    float s = 0.f;
    #pragma unroll
    for (int i = 0; i < 32; ++i) {
        size_t idx = (size_t)(tok0 + i) * DS + n;
        float v = u[idx] + u[idx + (size_t)MM * DS];
        s = fmaf(s, A, v);
    }
    spart[(size_t)bc * DS + n] = s;
}

__global__ void k2_scan(const float* __restrict__ spart, const float* __restrict__ logA,
                        float* __restrict__ hinit) {
    int b = blockIdx.x;              // 8 blocks
    int n = threadIdx.x;
    float Ap = expf(-32.f * expf(logA[n]));   // A_disc^32
    // prefetch all 64 chunk-partials into registers (static indices — no scratch),
    // then run the serial recurrence register-only (avoids 64x load-latency chain)
    float v[64];
    #pragma unroll
    for (int c = 0; c < 64; ++c)
        v[c] = spart[(size_t)(b * 64 + c) * DS + n];
    float e = 0.f;
    #pragma unroll
    for (int c = 0; c < 64; ++c) {
        hinit[(size_t)(b * 64 + c) * DS + n] = e;
        e = fmaf(e, Ap, v[c]);
    }
}

__global__ void k2_emit(const float* __restrict__ u, const float* __restrict__ logA,
                        const float* __restrict__ hinit, short* __restrict__ hsb) {
    int bc = blockIdx.x;
    int n = threadIdx.x;
    float A = expf(-expf(logA[n]));
    int tok0 = (bc >> 6) * TT + (bc & 63) * 32;
    float h = hinit[(size_t)bc * DS + n];
    #pragma unroll
    for (int i = 0; i < 32; ++i) {
        size_t idx = (size_t)(tok0 + i) * DS + n;
        float v = u[idx] + u[idx + (size_t)MM * DS];
        h = fmaf(h, A, v);
        hsb[idx] = f2bf(h);
    }
}

// ---------------------------------------------------------------- k3: y = hs@C^T + x*(1+D); out = LN
// grid 1024 blocks (16 tokens each), 512 threads (8 waves, wave w owns d in [w*256, w*256+256))
__global__ __launch_bounds__(512, 2) void k3_out(
        const short* __restrict__ hsb, const short* __restrict__ Cb,
        const float* __restrict__ x, const float* __restrict__ Dv,
        const float* __restrict__ lnw, const float* __restrict__ lnb,
        float* __restrict__ out) {
    __shared__ float redS[16], redQ[16];
    const int tok0 = blockIdx.x * 16;
    const int tid = threadIdx.x;
    const int wv = tid >> 6, l = tid & 63;
    const int r = l & 15, g = l >> 4;
    const int d0 = wv * 256;
    if (tid < 16) { redS[tid] = 0.f; redQ[tid] = 0.f; }

    f32x4 acc[16] = {};
    s16x8 af[4];
    #pragma unroll
    for (int ks = 0; ks < 4; ++ks)
        af[ks] = *reinterpret_cast<const s16x8*>(
            &hsb[(size_t)(tok0 + r) * DS + ks * 32 + g * 8]);
    #pragma unroll
    for (int ks = 0; ks < 4; ++ks) {
        #pragma unroll
        for (int dt = 0; dt < 16; ++dt) {
            s16x8 cf = *reinterpret_cast<const s16x8*>(
                &Cb[(size_t)(d0 + dt * 16 + r) * DS + ks * 32 + g * 8]);
            acc[dt] = __builtin_amdgcn_mfma_f32_16x16x32_bf16(af[ks], cf, acc[dt], 0, 0, 0);
        }
    }
    __syncthreads();   // LDS zero-init visible before atomics

    // epilogue: z = x*(1+D) + y ; accumulate per-row stats
    float zs[4] = {0.f, 0.f, 0.f, 0.f}, zq[4] = {0.f, 0.f, 0.f, 0.f};
    #pragma unroll
    for (int dt = 0; dt < 16; ++dt) {
        int d = d0 + dt * 16 + r;
        float dv = Dv[d];
        #pragma unroll
        for (int j = 0; j < 4; ++j) {
            int row = tok0 + g * 4 + j;
            float xv = x[(size_t)row * DM + d];
            float z = fmaf(xv, 1.f + dv, acc[dt][j]);
            acc[dt][j] = z;
            zs[j] += z;
            zq[j] = fmaf(z, z, zq[j]);
        }
    }
    // reduce across the 16 lanes of each row-group
    #pragma unroll
    for (int m = 8; m >= 1; m >>= 1) {
        #pragma unroll
        for (int j = 0; j < 4; ++j) {
            zs[j] += __shfl_xor(zs[j], m, 16);
            zq[j] += __shfl_xor(zq[j], m, 16);
        }
    }
    if (r == 0) {
        #pragma unroll
        for (int j = 0; j < 4; ++j) {
            atomicAdd(&redS[g * 4 + j], zs[j]);
            atomicAdd(&redQ[g * 4 + j], zq[j]);
        }
    }
    __syncthreads();
    float mu[4], rs[4];
    #pragma unroll
    for (int j = 0; j < 4; ++j) {
        float m_ = redS[g * 4 + j] * (1.f / DM);
        float v_ = redQ[g * 4 + j] * (1.f / DM) - m_ * m_;
        mu[j] = m_;
        rs[j] = rsqrtf(v_ + 1e-5f);
    }
    #pragma unroll
    for (int dt = 0; dt < 16; ++dt) {
        int d = d0 + dt * 16 + r;
        float w = lnw[d], bia = lnb[d];
        #pragma unroll
        for (int j = 0; j < 4; ++j) {
            int row = tok0 + g * 4 + j;
            out[(size_t)row * DM + d] = fmaf((acc[dt][j] - mu[j]) * rs[j], w, bia);
        }
    }
}

// ---------------------------------------------------------------- launch
extern "C" void kernel_launch(void* const* d_in, const int* in_sizes, int n_in,
                              void* d_out, int out_size, void* d_ws, size_t ws_size,
                              hipStream_t stream) {
    const float* x    = (const float*)d_in[0];
    const float* logA = (const float*)d_in[1];
    const float* Bm   = (const float*)d_in[2];
    const float* Cm   = (const float*)d_in[3];
    const float* Dv   = (const float*)d_in[4];
    const float* lnw  = (const float*)d_in[5];
    const float* lnb  = (const float*)d_in[6];
    float* out = (float*)d_out;

    char* ws = (char*)d_ws;
    float* u_parts = (float*)ws;                                   // 2 * 8 MiB
    short* hsb     = (short*)(ws + 16u * 1024 * 1024);             // 4 MiB
    short* Bb      = (short*)(ws + 20u * 1024 * 1024);             // 0.5 MiB
    short* Cb      = (short*)(ws + 20u * 1024 * 1024 + 512u * 1024);
    float* spart   = (float*)(ws + 21u * 1024 * 1024);             // 256 KiB
    float* hinit   = (float*)(ws + 21u * 1024 * 1024 + 256u * 1024);

    hipLaunchKernelGGL(k_cast,     dim3(512),      dim3(256), 0, stream, Bm, Cm, Bb, Cb);
    hipLaunchKernelGGL(k1_proj,    dim3(256, 2),   dim3(256), 0, stream, x, Bb, u_parts);
    hipLaunchKernelGGL(k2_partial, dim3(512),      dim3(128), 0, stream, u_parts, logA, spart);
    hipLaunchKernelGGL(k2_scan,    dim3(8),        dim3(128), 0, stream, spart, logA, hinit);
    hipLaunchKernelGGL(k2_emit,    dim3(512),      dim3(128), 0, stream, u_parts, logA, hinit, hsb);
    hipLaunchKernelGGL(k3_out,     dim3(1024),     dim3(512), 0, stream, hsb, Cb, x, Dv, lnw, lnb, out);
}